// Round 12
// baseline (81.723 us; speedup 1.0000x reference)
//
#include <hip/hip_runtime.h>

// SparseSelfAttention, algebraically reduced:
//   out[hd] = sum_g c_g * softmax(Q_hd K_g^T / 16) @ Vs[(2hd-g)%4]
//   Vs[head][j] = sum_{w=-2..2} v[head][(j+2w)%N]
//   c_g = 2 if (hd-g)%4==2 else 1
// N=2304 tokens, 4 heads, dh=64.
//
// k_flash v7 = R9/R10 proven body (K+V LDS dbuf 32KB, global_load_lds w16,
// counted vmcnt, 2 query-strips/wave, raw v_exp2, cvt_pkrtz, ones-row-MFMA
// denom) + SPLIT-K x8 (runtime CH, ws-gated): 2304 blocks = 9/CU grid so
// residency reaches the 4-block/CU VGPR cap -- R9's 30% occupancy was
// grid-limited (4.5/CU nominal, 2.4 time-avg) and the pipes (LDS 14us,
// MFMA 12us, trans 9us, VALU 8us) were SUMMING, not overlapping.
// R11 lesson: V-direct regressed (VGPR cliff / exposed L2 latency) - reverted.
// R5: no waves-per-EU clamp. R6: VGPR < 128. R8: cvt_pkrtz is __fp16.

#define N_TOK 2304
#define OUTC 256
#define HSZ (N_TOK * 64)   // halfs per head = 147456

typedef _Float16 half8 __attribute__((ext_vector_type(8)));
typedef _Float16 half4 __attribute__((ext_vector_type(4)));
typedef __fp16 fp16x2 __attribute__((ext_vector_type(2)));
typedef float f32x4 __attribute__((ext_vector_type(4)));

typedef __attribute__((address_space(3))) unsigned int as3_u32;
typedef __attribute__((address_space(1))) unsigned int as1_u32;

__device__ __forceinline__ f32x4 mfma16(half8 a, half8 b, f32x4 c) {
  return __builtin_amdgcn_mfma_f32_16x16x32_f16(a, b, c, 0, 0, 0);
}

__device__ __forceinline__ void gload_lds16(const _Float16* g, _Float16* l) {
  __builtin_amdgcn_global_load_lds((const as1_u32*)g, (as3_u32*)l, 16, 0, 0);
}

union H8U { half8 h8; fp16x2 h2[4]; };

// ---- kernel 1: fp32 -> fp16 conversion (vectorized x4) ----
__global__ __launch_bounds__(256) void k_convert(
    const float* __restrict__ x, const float* __restrict__ Wq,
    const float* __restrict__ Wk, const float* __restrict__ Wv,
    _Float16* __restrict__ xh, _Float16* __restrict__ Wh) {
  int i = blockIdx.x * 256 + threadIdx.x;
  if (i < N_TOK * OUTC / 4) {
    float4 f = ((const float4*)x)[i];
    half4 h; h[0] = (_Float16)f.x; h[1] = (_Float16)f.y; h[2] = (_Float16)f.z; h[3] = (_Float16)f.w;
    ((half4*)xh)[i] = h;
  }
  if (i < OUTC * OUTC / 4) {
    float4 a = ((const float4*)Wq)[i];
    float4 b = ((const float4*)Wk)[i];
    float4 c = ((const float4*)Wv)[i];
    half4 ha, hb, hc;
    ha[0]=(_Float16)a.x; ha[1]=(_Float16)a.y; ha[2]=(_Float16)a.z; ha[3]=(_Float16)a.w;
    hb[0]=(_Float16)b.x; hb[1]=(_Float16)b.y; hb[2]=(_Float16)b.z; hb[3]=(_Float16)b.w;
    hc[0]=(_Float16)c.x; hc[1]=(_Float16)c.y; hc[2]=(_Float16)c.z; hc[3]=(_Float16)c.w;
    ((half4*)Wh)[i] = ha;
    ((half4*)(Wh + OUTC*OUTC))[i] = hb;
    ((half4*)(Wh + 2*OUTC*OUTC))[i] = hc;
  }
}

// ---- kernel 2: QKV projection ----
// mat 0 -> Qh[hd][n][d] row-major, scaled by log2(e)/16 (exp2-domain softmax)
// mat 1 -> KF fragment-major: KF[hd*HSZ + ((t*4+c)*2+h)*512 + (g4*16+lr)*8 + ii]
//          = K[hd][t*64+16c+lr][32h+8*g4+ii]
// mat 2 -> VfT[o][n] f32 row-major
__global__ __launch_bounds__(256) void k_proj(
    const _Float16* __restrict__ xh, const _Float16* __restrict__ Wh,
    const float* __restrict__ bq, const float* __restrict__ bk,
    const float* __restrict__ bv,
    _Float16* __restrict__ Qh, _Float16* __restrict__ KF, float* __restrict__ VfT) {
  const int w = threadIdx.x >> 6, lane = threadIdx.x & 63;
  const int lr = lane & 15, lk = lane >> 4;
  const int n0 = blockIdx.x * 64 + w * 16;
  const int o0 = blockIdx.y * 64;
  const int mat = blockIdx.z;
  const _Float16* W = Wh + mat * (OUTC * OUTC);
  f32x4 acc[4] = {};
  const _Float16* xrow = xh + (n0 + lr) * OUTC + 8 * lk;
#pragma unroll
  for (int kk = 0; kk < 8; ++kk) {
    half8 a = *(const half8*)(xrow + 32 * kk);
#pragma unroll
    for (int c = 0; c < 4; ++c) {
      half8 b = *(const half8*)(W + (o0 + 16*c + lr) * OUTC + 32*kk + 8*lk);
      acc[c] = mfma16(a, b, acc[c]);
    }
  }
  const float* bias = (mat == 0) ? bq : (mat == 1) ? bk : bv;
  const int hd = blockIdx.y;   // head for mat 0/1
#pragma unroll
  for (int c = 0; c < 4; ++c) {
    int o = o0 + 16*c + lr;
    float bo = bias[o];
    if (mat == 2) {
      float4 vv;
      vv.x = acc[c][0] + bo; vv.y = acc[c][1] + bo;
      vv.z = acc[c][2] + bo; vv.w = acc[c][3] + bo;
      *(float4*)(VfT + (size_t)o * N_TOK + n0 + 4*lk) = vv;
    } else if (mat == 0) {
      int d = 16*c + lr;
      const float qs = 0.0625f * 1.4426950408889634f;   // (1/16) * log2(e)
#pragma unroll
      for (int r = 0; r < 4; ++r) {
        int n = n0 + 4*lk + r;
        Qh[((size_t)hd * N_TOK + n) * 64 + d] = (_Float16)((acc[c][r] + bo) * qs);
      }
    } else {
      int d = 16*c + lr;
      int h = d >> 5, g4K = (d >> 3) & 3, iiK = d & 7;
#pragma unroll
      for (int r = 0; r < 4; ++r) {
        int n = n0 + 4*lk + r;
        int tK = n >> 6, cK = (n >> 4) & 3, lrK = n & 15;
        KF[(size_t)hd * HSZ + ((tK*4 + cK)*2 + h)*512 + (g4K*16 + lrK)*8 + iiK] =
            (_Float16)(acc[c][r] + bo);
      }
    }
  }
}

// ---- kernel 3: smooth V over w-shifts, emit fragment-major + k-slot-permuted ----
// VF[vh*HSZ + t*4096 + f*8 + i]  (f = cc*128 + h*64 + g4*16 + lr)
//   = Vs[vh][16cc+lr][ t*64 + 32h + 16*(i>>2) + 4*g4 + (i&3) ]
__global__ __launch_bounds__(256) void k_smooth(
    const float* __restrict__ VfT, _Float16* __restrict__ VF) {
  const int t = blockIdx.x, vh = blockIdx.y;
  for (int f = threadIdx.x; f < 512; f += 256) {
    int cc = f >> 7, h = (f >> 6) & 1, g4 = (f >> 4) & 3, lr = f & 15;
    const float* src = VfT + (size_t)(vh*64 + 16*cc + lr) * N_TOK;
    int jbase = t*64 + 32*h + 4*g4;
    half8 out;
#pragma unroll
    for (int i = 0; i < 8; ++i) {
      int j = jbase + 16*(i >> 2) + (i & 3);
      float s = 0.f;
#pragma unroll
      for (int w = -4; w <= 4; w += 2) s += src[(j + w + N_TOK) % N_TOK];
      out[i] = (_Float16)s;
    }
    *(half8*)(VF + (size_t)vh * HSZ + (size_t)t * 4096 + f * 8) = out;
  }
}

// ---- kernel 4: flash attention, LDS tiles, counted vmcnt, runtime split-K ----
__global__ __launch_bounds__(256) void k_flash(
    const _Float16* __restrict__ Qh, const _Float16* __restrict__ KF,
    const _Float16* __restrict__ VF,
    _Float16* __restrict__ Opart, float* __restrict__ Lpart, int CH) {
  __shared__ __align__(16) _Float16 lds[2][8192];   // [buf][ K:0..4095 | V:4096..8191 ]
  const int wv = threadIdx.x >> 6, lane = threadIdx.x & 63;
  const int lr = lane & 15, g4 = lane >> 4;
  const int strip = blockIdx.x * 4 + wv;      // 0..71, 32 queries each
  const int n0 = strip * 32;
  const int pair = blockIdx.y;                // hd*4 + gk
  const int hd = pair >> 2, gk = pair & 3;
  const int ch = blockIdx.z;
  const int vh = (2*hd + 4 - gk) & 3;
  // chunk [t0, t0+len) of the 36 key tiles
  const int q36 = 36 / CH, r36 = 36 % CH;
  const int t0 = ch * q36 + (ch < r36 ? ch : r36);
  const int len = q36 + (ch < r36 ? 1 : 0);

  const _Float16* Qp = Qh + ((size_t)hd * N_TOK + n0 + lr) * 64 + 8*g4;
  const half8 qa0 = *(const half8*)(Qp);
  const half8 qa1 = *(const half8*)(Qp + 32);
  const half8 qb0 = *(const half8*)(Qp + 16*64);
  const half8 qb1 = *(const half8*)(Qp + 16*64 + 32);

  const _Float16* Kt = KF + (size_t)gk * HSZ + (size_t)t0 * 4096;
  const _Float16* Vt = VF + (size_t)vh * HSZ + (size_t)t0 * 4096;
  // wave wv stages one 4KB quarter of the 16KB tile-pair (lane-linear layout)
  const _Float16* gsrc = (wv < 2 ? Kt : Vt) + (wv & 1) * 2048 + lane * 8;
  const int ldsoff = (wv < 2 ? 0 : 4096) + (wv & 1) * 2048;

  f32x4 accA[4] = {}, accB[4] = {};
  f32x4 acclA = {}, acclB = {};
  half8 ones;
#pragma unroll
  for (int i = 0; i < 8; ++i) ones[i] = (_Float16)1.0f;

  auto stage = [&](int t, int b) {
    const _Float16* s = gsrc + (size_t)t * 4096;
    _Float16* d = &lds[b][ldsoff];
    gload_lds16(s,        d);
    gload_lds16(s + 512,  d + 512);
    gload_lds16(s + 1024, d + 1024);
    gload_lds16(s + 1536, d + 1536);
  };
  auto body = [&](int b) {
    const _Float16* ldsK = &lds[b][0]    + lane * 8;
    const _Float16* ldsV = &lds[b][4096] + lane * 8;
    f32x4 sA[4], sB[4];
    __builtin_amdgcn_s_setprio(1);
#pragma unroll
    for (int c = 0; c < 4; ++c) {
      half8 k0 = *(const half8*)(ldsK + c*1024);
      half8 k1 = *(const half8*)(ldsK + c*1024 + 512);
      f32x4 tA = {}; tA = mfma16(k0, qa0, tA); tA = mfma16(k1, qa1, tA); sA[c] = tA;
      f32x4 tB = {}; tB = mfma16(k0, qb0, tB); tB = mfma16(k1, qb1, tB); sB[c] = tB;
    }
    __builtin_amdgcn_s_setprio(0);
    // raw v_exp_f32 (log2-domain, |s| small -> no clamp needed) + packed cvt
    H8U a0, a1, b0, b1;
#pragma unroll
    for (int c = 0; c < 4; ++c) {
      float eA0 = __builtin_amdgcn_exp2f(sA[c][0]);
      float eA1 = __builtin_amdgcn_exp2f(sA[c][1]);
      float eA2 = __builtin_amdgcn_exp2f(sA[c][2]);
      float eA3 = __builtin_amdgcn_exp2f(sA[c][3]);
      float eB0 = __builtin_amdgcn_exp2f(sB[c][0]);
      float eB1 = __builtin_amdgcn_exp2f(sB[c][1]);
      float eB2 = __builtin_amdgcn_exp2f(sB[c][2]);
      float eB3 = __builtin_amdgcn_exp2f(sB[c][3]);
      H8U* da = (c < 2) ? &a0 : &a1;
      H8U* db = (c < 2) ? &b0 : &b1;
      int base = (c & 1) * 2;
      da->h2[base]     = __builtin_amdgcn_cvt_pkrtz(eA0, eA1);
      da->h2[base + 1] = __builtin_amdgcn_cvt_pkrtz(eA2, eA3);
      db->h2[base]     = __builtin_amdgcn_cvt_pkrtz(eB0, eB1);
      db->h2[base + 1] = __builtin_amdgcn_cvt_pkrtz(eB2, eB3);
    }
    __builtin_amdgcn_s_setprio(1);
#pragma unroll
    for (int cc = 0; cc < 4; ++cc) {
      half8 v0 = *(const half8*)(ldsV + cc*1024);
      half8 v1 = *(const half8*)(ldsV + cc*1024 + 512);
      accA[cc] = mfma16(v0, a0.h8, accA[cc]); accA[cc] = mfma16(v1, a1.h8, accA[cc]);
      accB[cc] = mfma16(v0, b0.h8, accB[cc]); accB[cc] = mfma16(v1, b1.h8, accB[cc]);
    }
    acclA = mfma16(ones, a0.h8, acclA); acclA = mfma16(ones, a1.h8, acclA);
    acclB = mfma16(ones, b0.h8, acclB); acclB = mfma16(ones, b1.h8, acclB);
    __builtin_amdgcn_s_setprio(0);
  };

  // T4 counted-vmcnt pipeline: prefetch stays in flight ACROSS the barrier.
  stage(0, 0);
#pragma unroll 1
  for (int t = 0; t < len; ++t) {
    if (t + 1 < len) {
      stage(t + 1, (t + 1) & 1);                       // 4 loads in flight
      asm volatile("s_waitcnt vmcnt(4)" ::: "memory"); // own stage(t) landed
    } else {
      asm volatile("s_waitcnt vmcnt(0)" ::: "memory");
    }
    __builtin_amdgcn_sched_barrier(0);
    __builtin_amdgcn_s_barrier();        // all waves' stage(t) landed
    __builtin_amdgcn_sched_barrier(0);
    body(t & 1);
    if (t + 1 < len) {
      __builtin_amdgcn_sched_barrier(0);
      __builtin_amdgcn_s_barrier();      // all readers of buf done before overwrite
    }
  }

  // epilogue: accl[0] is the full per-query denom (identical across r and g4)
  float invA = 1.0f / acclA[0];
  float invB = 1.0f / acclB[0];
  _Float16* Oa = Opart + (((size_t)ch * 16 + pair) * N_TOK + n0 + lr) * 64;
  _Float16* Ob = Oa + 16 * 64;
#pragma unroll
  for (int cc = 0; cc < 4; ++cc) {
    half4 ha, hb;
#pragma unroll
    for (int r = 0; r < 4; ++r) {
      ha[r] = (_Float16)(accA[cc][r] * invA);
      hb[r] = (_Float16)(accB[cc][r] * invB);
    }
    *(half4*)(Oa + 16*cc + 4*g4) = ha;
    *(half4*)(Ob + 16*cc + 4*g4) = hb;
  }
  if (g4 == 0) {
    Lpart[((size_t)ch * 16 + pair) * N_TOK + n0 + lr] = acclA[0];
    Lpart[((size_t)ch * 16 + pair) * N_TOK + n0 + 16 + lr] = acclB[0];
  }
}

// ---- kernel 5: merge split-K chunks (l-weighted), weight by c_g, sum over gk ----
__global__ __launch_bounds__(256) void k_combine(
    const _Float16* __restrict__ Opart, const float* __restrict__ Lpart,
    float* __restrict__ out, int CH) {
  int gid = blockIdx.x * 256 + threadIdx.x;   // 73728 total
  int hd = gid / (N_TOK * 8);
  int rem = gid % (N_TOK * 8);
  int n = rem >> 3, db = (rem & 7) * 8;
  float acc[8] = {};
#pragma unroll
  for (int gk = 0; gk < 4; ++gk) {
    float cg = (((hd - gk) & 3) == 2) ? 2.0f : 1.0f;
    int pair = hd * 4 + gk;
    float la[8], lsum = 0.f;
    for (int c = 0; c < CH; ++c) {
      la[c] = Lpart[((size_t)c * 16 + pair) * N_TOK + n];
      lsum += la[c];
    }
    float rs = cg / lsum;
    for (int c = 0; c < CH; ++c) {
      half8 v = *(const half8*)(Opart + (((size_t)c * 16 + pair) * N_TOK + n) * 64 + db);
      float w = la[c] * rs;
#pragma unroll
      for (int i = 0; i < 8; ++i) acc[i] += w * (float)v[i];
    }
  }
  float* dst = out + (size_t)n * OUTC + hd * 64 + db;
  float4 r0, r1;
  r0.x = acc[0]; r0.y = acc[1]; r0.z = acc[2]; r0.w = acc[3];
  r1.x = acc[4]; r1.y = acc[5]; r1.z = acc[6]; r1.w = acc[7];
  *(float4*)(dst)     = r0;
  *(float4*)(dst + 4) = r1;
}

extern "C" void kernel_launch(void* const* d_in, const int* in_sizes, int n_in,
                              void* d_out, int out_size, void* d_ws, size_t ws_size,
                              hipStream_t stream) {
  (void)in_sizes; (void)n_in; (void)out_size;
  const float* x  = (const float*)d_in[0];
  const float* Wq = (const float*)d_in[1];
  const float* bq = (const float*)d_in[2];
  const float* Wk = (const float*)d_in[3];
  const float* bk = (const float*)d_in[4];
  const float* Wv = (const float*)d_in[5];
  const float* bv = (const float*)d_in[6];

  char* ws = (char*)d_ws;
  _Float16* xh  = (_Float16*)(ws);              // 1,179,648 B (dead after k_proj)
  float*    Lp  = (float*)   (ws);              // reuses xh region (<=1,179,648 B)
  _Float16* Wh  = (_Float16*)(ws + 1179648);    //   393,216 B
  _Float16* Qh  = (_Float16*)(ws + 1572864);    // 1,179,648 B
  _Float16* KF  = (_Float16*)(ws + 2752512);    // 1,179,648 B (fragment-major)
  float*    VfT = (float*)   (ws + 3932160);    // 2,359,296 B
  _Float16* VF  = (_Float16*)(ws + 6291456);    // 1,179,648 B (fragment-major)
  _Float16* Op  = (_Float16*)(ws + 7471104);    // CH*16*N_TOK*64*2 B
  float* out = (float*)d_out;

  // split-K width gated on workspace: CH=8 needs Op end = 45,219,840 B
  const int CH = (ws_size >= (size_t)45219840) ? 8 : 4;

  k_convert<<<dim3(576), dim3(256), 0, stream>>>(x, Wq, Wk, Wv, xh, Wh);
  k_proj   <<<dim3(36, 4, 3), dim3(256), 0, stream>>>(xh, Wh, bq, bk, bv, Qh, KF, VfT);
  k_smooth <<<dim3(36, 4), dim3(256), 0, stream>>>(VfT, VF);
  k_flash  <<<dim3(18, 16, CH), dim3(256), 0, stream>>>(Qh, KF, VF, Op, Lp, CH);
  k_combine<<<dim3(288), dim3(256), 0, stream>>>(Op, Lp, out, CH);
}

// Round 13
// 69.123 us; speedup vs baseline: 1.1823x; 1.1823x over previous
//
#include <hip/hip_runtime.h>

// SparseSelfAttention, algebraically reduced:
//   out[hd] = sum_g c_g * softmax(Q_hd K_g^T / 16) @ Vs[(2hd-g)%4]
//   Vs[head][j] = sum_{w=-2..2} v[head][(j+2w)%N]
//   c_g = 2 if (hd-g)%4==2 else 1
// N=2304 tokens, 4 heads, dh=64.
//
// k_flash v8 = R10-proven body (K+V LDS dbuf 32KB, global_load_lds w16,
// counted vmcnt + raw barriers, 2 query-strips/wave, raw v_exp2, cvt_pkrtz,
// ones-row-MFMA denom, split-K x4) + __launch_bounds__(256,2):
// R7 showed VGPR_Count=44 with ~90 regs of live state -> compiler put MFMA
// accumulators in AGPRs and shuttled v_accvgpr_read/write around every MFMA
// (~1000 hidden VALU-cyc/body, the 55% VALUBusy mystery). (256,2) grants a
// 128-VGPR budget (R5's formula: budget=256/min_waves) -> all-VGPR, no
// shuttle, still 4 blocks/CU.
// R12 lesson: split-K x8 regressed (2x Opart traffic + 2x prologues) - reverted.
// R11 lesson: V-direct regressed - K+V stay in LDS. R8: cvt_pkrtz is __fp16.

#define N_TOK 2304
#define OUTC 256
#define HSZ (N_TOK * 64)   // halfs per head = 147456

typedef _Float16 half8 __attribute__((ext_vector_type(8)));
typedef _Float16 half4 __attribute__((ext_vector_type(4)));
typedef __fp16 fp16x2 __attribute__((ext_vector_type(2)));
typedef float f32x4 __attribute__((ext_vector_type(4)));

typedef __attribute__((address_space(3))) unsigned int as3_u32;
typedef __attribute__((address_space(1))) unsigned int as1_u32;

__device__ __forceinline__ f32x4 mfma16(half8 a, half8 b, f32x4 c) {
  return __builtin_amdgcn_mfma_f32_16x16x32_f16(a, b, c, 0, 0, 0);
}

__device__ __forceinline__ void gload_lds16(const _Float16* g, _Float16* l) {
  __builtin_amdgcn_global_load_lds((const as1_u32*)g, (as3_u32*)l, 16, 0, 0);
}

union H8U { half8 h8; fp16x2 h2[4]; };

__device__ __forceinline__ half8 pack_f32x8(const float* e) {
  H8U u;
  u.h2[0] = __builtin_amdgcn_cvt_pkrtz(e[0], e[1]);
  u.h2[1] = __builtin_amdgcn_cvt_pkrtz(e[2], e[3]);
  u.h2[2] = __builtin_amdgcn_cvt_pkrtz(e[4], e[5]);
  u.h2[3] = __builtin_amdgcn_cvt_pkrtz(e[6], e[7]);
  return u.h8;
}

// ---- kernel 1: QKV projection (reads f32 x/W directly, converts inline) ----
// mat 0 -> Qh[hd][n][d] row-major, scaled by log2(e)/16 (exp2-domain softmax)
// mat 1 -> KF fragment-major: KF[hd*HSZ + ((t*4+c)*2+h)*512 + (g4*16+lr)*8 + ii]
//          = K[hd][t*64+16c+lr][32h+8*g4+ii]
// mat 2 -> VfT[o][n] f32 row-major
__global__ __launch_bounds__(256) void k_proj(
    const float* __restrict__ x, const float* __restrict__ Wq,
    const float* __restrict__ Wk, const float* __restrict__ Wv,
    const float* __restrict__ bq, const float* __restrict__ bk,
    const float* __restrict__ bv,
    _Float16* __restrict__ Qh, _Float16* __restrict__ KF, float* __restrict__ VfT) {
  const int w = threadIdx.x >> 6, lane = threadIdx.x & 63;
  const int lr = lane & 15, lk = lane >> 4;
  const int n0 = blockIdx.x * 64 + w * 16;
  const int o0 = blockIdx.y * 64;
  const int mat = blockIdx.z;
  const float* W = (mat == 0) ? Wq : (mat == 1) ? Wk : Wv;
  f32x4 acc[4] = {};
  const float* xrow = x + (size_t)(n0 + lr) * OUTC + 8 * lk;
#pragma unroll
  for (int kk = 0; kk < 8; ++kk) {
    float af[8];
    *(float4*)&af[0] = *(const float4*)(xrow + 32 * kk);
    *(float4*)&af[4] = *(const float4*)(xrow + 32 * kk + 4);
    half8 a = pack_f32x8(af);
#pragma unroll
    for (int c = 0; c < 4; ++c) {
      const float* wrow = W + (size_t)(o0 + 16*c + lr) * OUTC + 32*kk + 8*lk;
      float bf[8];
      *(float4*)&bf[0] = *(const float4*)(wrow);
      *(float4*)&bf[4] = *(const float4*)(wrow + 4);
      half8 b = pack_f32x8(bf);
      acc[c] = mfma16(a, b, acc[c]);
    }
  }
  const float* bias = (mat == 0) ? bq : (mat == 1) ? bk : bv;
  const int hd = blockIdx.y;   // head for mat 0/1
#pragma unroll
  for (int c = 0; c < 4; ++c) {
    int o = o0 + 16*c + lr;
    float bo = bias[o];
    if (mat == 2) {
      float4 vv;
      vv.x = acc[c][0] + bo; vv.y = acc[c][1] + bo;
      vv.z = acc[c][2] + bo; vv.w = acc[c][3] + bo;
      *(float4*)(VfT + (size_t)o * N_TOK + n0 + 4*lk) = vv;
    } else if (mat == 0) {
      int d = 16*c + lr;
      const float qs = 0.0625f * 1.4426950408889634f;   // (1/16) * log2(e)
#pragma unroll
      for (int r = 0; r < 4; ++r) {
        int n = n0 + 4*lk + r;
        Qh[((size_t)hd * N_TOK + n) * 64 + d] = (_Float16)((acc[c][r] + bo) * qs);
      }
    } else {
      int d = 16*c + lr;
      int h = d >> 5, g4K = (d >> 3) & 3, iiK = d & 7;
#pragma unroll
      for (int r = 0; r < 4; ++r) {
        int n = n0 + 4*lk + r;
        int tK = n >> 6, cK = (n >> 4) & 3, lrK = n & 15;
        KF[(size_t)hd * HSZ + ((tK*4 + cK)*2 + h)*512 + (g4K*16 + lrK)*8 + iiK] =
            (_Float16)(acc[c][r] + bo);
      }
    }
  }
}

// ---- kernel 2: smooth V over w-shifts, emit fragment-major + k-slot-permuted ----
// VF[vh*HSZ + t*4096 + f*8 + i]  (f = cc*128 + h*64 + g4*16 + lr)
//   = Vs[vh][16cc+lr][ t*64 + 32h + 16*(i>>2) + 4*g4 + (i&3) ]
__global__ __launch_bounds__(256) void k_smooth(
    const float* __restrict__ VfT, _Float16* __restrict__ VF) {
  const int t = blockIdx.x, vh = blockIdx.y;
  for (int f = threadIdx.x; f < 512; f += 256) {
    int cc = f >> 7, h = (f >> 6) & 1, g4 = (f >> 4) & 3, lr = f & 15;
    const float* src = VfT + (size_t)(vh*64 + 16*cc + lr) * N_TOK;
    int jbase = t*64 + 32*h + 4*g4;
    half8 out;
#pragma unroll
    for (int i = 0; i < 8; ++i) {
      int j = jbase + 16*(i >> 2) + (i & 3);
      float s = 0.f;
#pragma unroll
      for (int w = -4; w <= 4; w += 2) s += src[(j + w + N_TOK) % N_TOK];
      out[i] = (_Float16)s;
    }
    *(half8*)(VF + (size_t)vh * HSZ + (size_t)t * 4096 + f * 8) = out;
  }
}

// ---- kernel 3: flash attention, LDS tiles, counted vmcnt, split-K x4 ----
__global__ __launch_bounds__(256, 2) void k_flash(
    const _Float16* __restrict__ Qh, const _Float16* __restrict__ KF,
    const _Float16* __restrict__ VF,
    _Float16* __restrict__ Opart, float* __restrict__ Lpart) {
  __shared__ __align__(16) _Float16 lds[2][8192];   // [buf][ K:0..4095 | V:4096..8191 ]
  const int wv = threadIdx.x >> 6, lane = threadIdx.x & 63;
  const int lr = lane & 15, g4 = lane >> 4;
  const int strip = blockIdx.x * 4 + wv;      // 0..71, 32 queries each
  const int n0 = strip * 32;
  const int pair = blockIdx.y;                // hd*4 + gk
  const int hd = pair >> 2, gk = pair & 3;
  const int chunk = blockIdx.z;               // 9 tiles each
  const int vh = (2*hd + 4 - gk) & 3;

  const _Float16* Qp = Qh + ((size_t)hd * N_TOK + n0 + lr) * 64 + 8*g4;
  const half8 qa0 = *(const half8*)(Qp);
  const half8 qa1 = *(const half8*)(Qp + 32);
  const half8 qb0 = *(const half8*)(Qp + 16*64);
  const half8 qb1 = *(const half8*)(Qp + 16*64 + 32);

  const _Float16* Kt = KF + (size_t)gk * HSZ + (size_t)chunk * 9 * 4096;
  const _Float16* Vt = VF + (size_t)vh * HSZ + (size_t)chunk * 9 * 4096;
  // wave wv stages one 4KB quarter of the 16KB tile-pair (lane-linear layout)
  const _Float16* gsrc = (wv < 2 ? Kt : Vt) + (wv & 1) * 2048 + lane * 8;
  const int ldsoff = (wv < 2 ? 0 : 4096) + (wv & 1) * 2048;

  f32x4 accA[4] = {}, accB[4] = {};
  f32x4 acclA = {}, acclB = {};
  half8 ones;
#pragma unroll
  for (int i = 0; i < 8; ++i) ones[i] = (_Float16)1.0f;

  auto stage = [&](int t, int b) {
    const _Float16* s = gsrc + (size_t)t * 4096;
    _Float16* d = &lds[b][ldsoff];
    gload_lds16(s,        d);
    gload_lds16(s + 512,  d + 512);
    gload_lds16(s + 1024, d + 1024);
    gload_lds16(s + 1536, d + 1536);
  };
  auto body = [&](int b) {
    const _Float16* ldsK = &lds[b][0]    + lane * 8;
    const _Float16* ldsV = &lds[b][4096] + lane * 8;
    f32x4 sA[4], sB[4];
    __builtin_amdgcn_s_setprio(1);
#pragma unroll
    for (int c = 0; c < 4; ++c) {
      half8 k0 = *(const half8*)(ldsK + c*1024);
      half8 k1 = *(const half8*)(ldsK + c*1024 + 512);
      f32x4 tA = {}; tA = mfma16(k0, qa0, tA); tA = mfma16(k1, qa1, tA); sA[c] = tA;
      f32x4 tB = {}; tB = mfma16(k0, qb0, tB); tB = mfma16(k1, qb1, tB); sB[c] = tB;
    }
    __builtin_amdgcn_s_setprio(0);
    // raw v_exp_f32 (log2-domain, |s| small -> no clamp needed) + packed cvt
    H8U a0, a1, b0, b1;
#pragma unroll
    for (int c = 0; c < 4; ++c) {
      float eA0 = __builtin_amdgcn_exp2f(sA[c][0]);
      float eA1 = __builtin_amdgcn_exp2f(sA[c][1]);
      float eA2 = __builtin_amdgcn_exp2f(sA[c][2]);
      float eA3 = __builtin_amdgcn_exp2f(sA[c][3]);
      float eB0 = __builtin_amdgcn_exp2f(sB[c][0]);
      float eB1 = __builtin_amdgcn_exp2f(sB[c][1]);
      float eB2 = __builtin_amdgcn_exp2f(sB[c][2]);
      float eB3 = __builtin_amdgcn_exp2f(sB[c][3]);
      H8U* da = (c < 2) ? &a0 : &a1;
      H8U* db = (c < 2) ? &b0 : &b1;
      int base = (c & 1) * 2;
      da->h2[base]     = __builtin_amdgcn_cvt_pkrtz(eA0, eA1);
      da->h2[base + 1] = __builtin_amdgcn_cvt_pkrtz(eA2, eA3);
      db->h2[base]     = __builtin_amdgcn_cvt_pkrtz(eB0, eB1);
      db->h2[base + 1] = __builtin_amdgcn_cvt_pkrtz(eB2, eB3);
    }
    __builtin_amdgcn_s_setprio(1);
#pragma unroll
    for (int cc = 0; cc < 4; ++cc) {
      half8 v0 = *(const half8*)(ldsV + cc*1024);
      half8 v1 = *(const half8*)(ldsV + cc*1024 + 512);
      accA[cc] = mfma16(v0, a0.h8, accA[cc]); accA[cc] = mfma16(v1, a1.h8, accA[cc]);
      accB[cc] = mfma16(v0, b0.h8, accB[cc]); accB[cc] = mfma16(v1, b1.h8, accB[cc]);
    }
    acclA = mfma16(ones, a0.h8, acclA); acclA = mfma16(ones, a1.h8, acclA);
    acclB = mfma16(ones, b0.h8, acclB); acclB = mfma16(ones, b1.h8, acclB);
    __builtin_amdgcn_s_setprio(0);
  };

  // T4 counted-vmcnt pipeline: prefetch stays in flight ACROSS the barrier.
  stage(0, 0);
#pragma unroll 1
  for (int t = 0; t < 9; ++t) {
    if (t < 8) {
      stage(t + 1, (t + 1) & 1);                       // 4 loads in flight
      asm volatile("s_waitcnt vmcnt(4)" ::: "memory"); // own stage(t) landed
    } else {
      asm volatile("s_waitcnt vmcnt(0)" ::: "memory");
    }
    __builtin_amdgcn_sched_barrier(0);
    __builtin_amdgcn_s_barrier();        // all waves' stage(t) landed
    __builtin_amdgcn_sched_barrier(0);
    body(t & 1);
    if (t < 8) {
      __builtin_amdgcn_sched_barrier(0);
      __builtin_amdgcn_s_barrier();      // all readers of buf done before overwrite
    }
  }

  // epilogue: accl[0] is the full per-query denom (identical across r and g4)
  float invA = 1.0f / acclA[0];
  float invB = 1.0f / acclB[0];
  _Float16* Oa = Opart + (((size_t)chunk * 16 + pair) * N_TOK + n0 + lr) * 64;
  _Float16* Ob = Oa + 16 * 64;
#pragma unroll
  for (int cc = 0; cc < 4; ++cc) {
    half4 ha, hb;
#pragma unroll
    for (int r = 0; r < 4; ++r) {
      ha[r] = (_Float16)(accA[cc][r] * invA);
      hb[r] = (_Float16)(accB[cc][r] * invB);
    }
    *(half4*)(Oa + 16*cc + 4*g4) = ha;
    *(half4*)(Ob + 16*cc + 4*g4) = hb;
  }
  if (g4 == 0) {
    Lpart[((size_t)chunk * 16 + pair) * N_TOK + n0 + lr] = acclA[0];
    Lpart[((size_t)chunk * 16 + pair) * N_TOK + n0 + 16 + lr] = acclB[0];
  }
}

// ---- kernel 4: merge split-K chunks (l-weighted), weight by c_g, sum over gk ----
__global__ __launch_bounds__(256) void k_combine(
    const _Float16* __restrict__ Opart, const float* __restrict__ Lpart,
    float* __restrict__ out) {
  int gid = blockIdx.x * 256 + threadIdx.x;   // 73728 total
  int hd = gid / (N_TOK * 8);
  int rem = gid % (N_TOK * 8);
  int n = rem >> 3, db = (rem & 7) * 8;
  float acc[8] = {};
#pragma unroll
  for (int gk = 0; gk < 4; ++gk) {
    float cg = (((hd - gk) & 3) == 2) ? 2.0f : 1.0f;
    int pair = hd * 4 + gk;
    float la[4], lsum = 0.f;
#pragma unroll
    for (int ch = 0; ch < 4; ++ch) {
      la[ch] = Lpart[((size_t)ch * 16 + pair) * N_TOK + n];
      lsum += la[ch];
    }
    float rs = cg / lsum;
#pragma unroll
    for (int ch = 0; ch < 4; ++ch) {
      half8 v = *(const half8*)(Opart + (((size_t)ch * 16 + pair) * N_TOK + n) * 64 + db);
      float w = la[ch] * rs;
#pragma unroll
      for (int i = 0; i < 8; ++i) acc[i] += w * (float)v[i];
    }
  }
  float* dst = out + (size_t)n * OUTC + hd * 64 + db;
  float4 r0, r1;
  r0.x = acc[0]; r0.y = acc[1]; r0.z = acc[2]; r0.w = acc[3];
  r1.x = acc[4]; r1.y = acc[5]; r1.z = acc[6]; r1.w = acc[7];
  *(float4*)(dst)     = r0;
  *(float4*)(dst + 4) = r1;
}

extern "C" void kernel_launch(void* const* d_in, const int* in_sizes, int n_in,
                              void* d_out, int out_size, void* d_ws, size_t ws_size,
                              hipStream_t stream) {
  (void)in_sizes; (void)n_in; (void)out_size; (void)ws_size;
  const float* x  = (const float*)d_in[0];
  const float* Wq = (const float*)d_in[1];
  const float* bq = (const float*)d_in[2];
  const float* Wk = (const float*)d_in[3];
  const float* bk = (const float*)d_in[4];
  const float* Wv = (const float*)d_in[5];
  const float* bv = (const float*)d_in[6];

  char* ws = (char*)d_ws;
  float*    Lp  = (float*)   (ws);              //   589,824 B
  _Float16* Qh  = (_Float16*)(ws + 1179648);    // 1,179,648 B
  _Float16* KF  = (_Float16*)(ws + 2359296);    // 1,179,648 B (fragment-major)
  float*    VfT = (float*)   (ws + 3538944);    // 2,359,296 B
  _Float16* VF  = (_Float16*)(ws + 5898240);    // 1,179,648 B (fragment-major)
  _Float16* Op  = (_Float16*)(ws + 7077888);    // 9,437,184 B (ends 16,515,072)
  float* out = (float*)d_out;

  k_proj   <<<dim3(36, 4, 3), dim3(256), 0, stream>>>(x, Wq, Wk, Wv, bq, bk, bv, Qh, KF, VfT);
  k_smooth <<<dim3(36, 4), dim3(256), 0, stream>>>(VfT, VF);
  k_flash  <<<dim3(18, 16, 4), dim3(256), 0, stream>>>(Qh, KF, VF, Op, Lp);
  k_combine<<<dim3(288), dim3(256), 0, stream>>>(Op, Lp, out);
}

// Round 14
// 67.744 us; speedup vs baseline: 1.2063x; 1.0204x over previous
//
#include <hip/hip_runtime.h>

// SparseSelfAttention, algebraically reduced:
//   out[hd] = sum_g c_g * softmax(Q_hd K_g^T / 16) @ Vs[(2hd-g)%4]
//   Vs[head][j] = sum_{w=-2..2} v[head][(j+2w)%N]
//   c_g = 2 if (hd-g)%4==2 else 1
// N=2304 tokens, 4 heads, dh=64.
//
// R14: attack the ~32us of NON-flash time (never profiled; top-5 polluted).
// k_smooth did 2.9M scattered scalar f32 loads (5 per element, permuted rows)
// and k_proj's Q/K epilogues did 589k scattered 2B stores each -- the same
// TA-bound pattern that cost k_flash 167->45us in R3->R4. Both now go through
// LDS: coalesced global reads/writes, scatter only inside LDS.
// k_flash = R10's proven body, untouched (67.3us total best).
// R12: split-K x8 regressed. R11: V-direct regressed. R6: VGPR<128.
// R5: no waves-per-EU clamp on k_flash. R8: cvt_pkrtz is __fp16.

#define N_TOK 2304
#define OUTC 256
#define HSZ (N_TOK * 64)   // halfs per head = 147456

typedef _Float16 half8 __attribute__((ext_vector_type(8)));
typedef _Float16 half4 __attribute__((ext_vector_type(4)));
typedef __fp16 fp16x2 __attribute__((ext_vector_type(2)));
typedef float f32x4 __attribute__((ext_vector_type(4)));

typedef __attribute__((address_space(3))) unsigned int as3_u32;
typedef __attribute__((address_space(1))) unsigned int as1_u32;

__device__ __forceinline__ f32x4 mfma16(half8 a, half8 b, f32x4 c) {
  return __builtin_amdgcn_mfma_f32_16x16x32_f16(a, b, c, 0, 0, 0);
}

__device__ __forceinline__ void gload_lds16(const _Float16* g, _Float16* l) {
  __builtin_amdgcn_global_load_lds((const as1_u32*)g, (as3_u32*)l, 16, 0, 0);
}

union H8U { half8 h8; fp16x2 h2[4]; };

__device__ __forceinline__ half8 pack_f32x8(const float* e) {
  H8U u;
  u.h2[0] = __builtin_amdgcn_cvt_pkrtz(e[0], e[1]);
  u.h2[1] = __builtin_amdgcn_cvt_pkrtz(e[2], e[3]);
  u.h2[2] = __builtin_amdgcn_cvt_pkrtz(e[4], e[5]);
  u.h2[3] = __builtin_amdgcn_cvt_pkrtz(e[6], e[7]);
  return u.h8;
}

// ---- kernel 1: QKV projection (f32 in, LDS-staged coalesced epilogues) ----
// mat 0 -> Qh[hd][n][d] row-major, scaled log2(e)/16; contiguous 8KB/block
// mat 1 -> KF fragment-major; block (bx,hd) owns contiguous KF[hd*HSZ+bx*4096 ..+4096)
// mat 2 -> VfT[o][n] f32 row-major (float4 direct writes)
__global__ __launch_bounds__(256) void k_proj(
    const float* __restrict__ x, const float* __restrict__ Wq,
    const float* __restrict__ Wk, const float* __restrict__ Wv,
    const float* __restrict__ bq, const float* __restrict__ bk,
    const float* __restrict__ bv,
    _Float16* __restrict__ Qh, _Float16* __restrict__ KF, float* __restrict__ VfT) {
  __shared__ _Float16 stg[4096];
  const int w = threadIdx.x >> 6, lane = threadIdx.x & 63;
  const int lr = lane & 15, lk = lane >> 4;
  const int n0 = blockIdx.x * 64 + w * 16;
  const int o0 = blockIdx.y * 64;
  const int mat = blockIdx.z;
  const float* W = (mat == 0) ? Wq : (mat == 1) ? Wk : Wv;
  f32x4 acc[4] = {};
  const float* xrow = x + (size_t)(n0 + lr) * OUTC + 8 * lk;
#pragma unroll
  for (int kk = 0; kk < 8; ++kk) {
    float af[8];
    *(float4*)&af[0] = *(const float4*)(xrow + 32 * kk);
    *(float4*)&af[4] = *(const float4*)(xrow + 32 * kk + 4);
    half8 a = pack_f32x8(af);
#pragma unroll
    for (int c = 0; c < 4; ++c) {
      const float* wrow = W + (size_t)(o0 + 16*c + lr) * OUTC + 32*kk + 8*lk;
      float bf[8];
      *(float4*)&bf[0] = *(const float4*)(wrow);
      *(float4*)&bf[4] = *(const float4*)(wrow + 4);
      half8 b = pack_f32x8(bf);
      acc[c] = mfma16(a, b, acc[c]);
    }
  }
  const float* bias = (mat == 0) ? bq : (mat == 1) ? bk : bv;
  const int hd = blockIdx.y;   // head for mat 0/1

  if (mat == 2) {
#pragma unroll
    for (int c = 0; c < 4; ++c) {
      int o = o0 + 16*c + lr;
      float bo = bias[o];
      float4 vv;
      vv.x = acc[c][0] + bo; vv.y = acc[c][1] + bo;
      vv.z = acc[c][2] + bo; vv.w = acc[c][3] + bo;
      *(float4*)(VfT + (size_t)o * N_TOK + n0 + 4*lk) = vv;
    }
    return;
  }

  if (mat == 0) {
    // stage [64 n][64 d] halves, then contiguous 8KB stream write
    const float qs = 0.0625f * 1.4426950408889634f;   // (1/16) * log2(e)
#pragma unroll
    for (int c = 0; c < 4; ++c) {
      float bo = bias[o0 + 16*c + lr];
      int d = 16*c + lr;
#pragma unroll
      for (int r = 0; r < 4; ++r)
        stg[(w*16 + 4*lk + r) * 64 + d] = (_Float16)((acc[c][r] + bo) * qs);
    }
    __syncthreads();
    _Float16* dst = Qh + ((size_t)hd * N_TOK + blockIdx.x * 64) * 64;
    ((half8*)dst)[threadIdx.x]       = ((const half8*)stg)[threadIdx.x];
    ((half8*)dst)[256 + threadIdx.x] = ((const half8*)stg)[256 + threadIdx.x];
  } else {
    // KF local idx = (w*2+h)*512 + (g4K*16 + 4*lk + r)*8 + iiK  (cK == w)
#pragma unroll
    for (int c = 0; c < 4; ++c) {
      float bo = bias[o0 + 16*c + lr];
      int d = 16*c + lr;
      int h = d >> 5, g4K = (d >> 3) & 3, iiK = d & 7;
#pragma unroll
      for (int r = 0; r < 4; ++r)
        stg[(w*2 + h)*512 + (g4K*16 + 4*lk + r)*8 + iiK] = (_Float16)(acc[c][r] + bo);
    }
    __syncthreads();
    _Float16* dst = KF + (size_t)hd * HSZ + (size_t)blockIdx.x * 4096;
    ((half8*)dst)[threadIdx.x]       = ((const half8*)stg)[threadIdx.x];
    ((half8*)dst)[256 + threadIdx.x] = ((const half8*)stg)[256 + threadIdx.x];
  }
}

// ---- kernel 2: smooth V over w-shifts -> fragment-major VF, LDS-staged ----
// VF[vh*HSZ + t*4096 + f*8 + i]  (f = cc*128 + h*64 + g4*16 + lr)
//   = Vs[vh][16cc+lr][ t*64 + 32h + 16*(i>>2) + 4*g4 + (i&3) ]
__global__ __launch_bounds__(256) void k_smooth(
    const float* __restrict__ VfT, _Float16* __restrict__ VF) {
  __shared__ float Ls[64][76];   // 72-col window + pad (banks spread)
  const int t = blockIdx.x, vh = blockIdx.y;
  // coalesced stage: 64 rows x 72 cols, consecutive threads -> consecutive cols
  for (int idx = threadIdx.x; idx < 64 * 72; idx += 256) {
    int rr = idx / 72, cc = idx % 72;
    int j = t*64 - 4 + cc; j = (j + N_TOK) % N_TOK;
    Ls[rr][cc] = VfT[(size_t)(vh*64 + rr) * N_TOK + j];
  }
  __syncthreads();
  for (int f = threadIdx.x; f < 512; f += 256) {
    int cc = f >> 7, h = (f >> 6) & 1, g4 = (f >> 4) & 3, lr = f & 15;
    int row = 16*cc + lr;
    int base = 4 + 32*h + 4*g4;
    half8 out;
#pragma unroll
    for (int i = 0; i < 8; ++i) {
      int loc = base + 16*(i >> 2) + (i & 3);
      float s = Ls[row][loc-4] + Ls[row][loc-2] + Ls[row][loc]
              + Ls[row][loc+2] + Ls[row][loc+4];
      out[i] = (_Float16)s;
    }
    *(half8*)(VF + (size_t)vh * HSZ + (size_t)t * 4096 + f * 8) = out;
  }
}

// ---- kernel 3: flash attention (R10-proven), LDS tiles, counted vmcnt ----
__global__ __launch_bounds__(256) void k_flash(
    const _Float16* __restrict__ Qh, const _Float16* __restrict__ KF,
    const _Float16* __restrict__ VF,
    _Float16* __restrict__ Opart, float* __restrict__ Lpart) {
  __shared__ __align__(16) _Float16 lds[2][8192];   // [buf][ K:0..4095 | V:4096..8191 ]
  const int wv = threadIdx.x >> 6, lane = threadIdx.x & 63;
  const int lr = lane & 15, g4 = lane >> 4;
  const int strip = blockIdx.x * 4 + wv;      // 0..71, 32 queries each
  const int n0 = strip * 32;
  const int pair = blockIdx.y;                // hd*4 + gk
  const int hd = pair >> 2, gk = pair & 3;
  const int chunk = blockIdx.z;               // 9 tiles each
  const int vh = (2*hd + 4 - gk) & 3;

  const _Float16* Qp = Qh + ((size_t)hd * N_TOK + n0 + lr) * 64 + 8*g4;
  const half8 qa0 = *(const half8*)(Qp);
  const half8 qa1 = *(const half8*)(Qp + 32);
  const half8 qb0 = *(const half8*)(Qp + 16*64);
  const half8 qb1 = *(const half8*)(Qp + 16*64 + 32);

  const _Float16* Kt = KF + (size_t)gk * HSZ + (size_t)chunk * 9 * 4096;
  const _Float16* Vt = VF + (size_t)vh * HSZ + (size_t)chunk * 9 * 4096;
  const _Float16* gsrc = (wv < 2 ? Kt : Vt) + (wv & 1) * 2048 + lane * 8;
  const int ldsoff = (wv < 2 ? 0 : 4096) + (wv & 1) * 2048;

  f32x4 accA[4] = {}, accB[4] = {};
  f32x4 acclA = {}, acclB = {};
  half8 ones;
#pragma unroll
  for (int i = 0; i < 8; ++i) ones[i] = (_Float16)1.0f;

  auto stage = [&](int t, int b) {
    const _Float16* s = gsrc + (size_t)t * 4096;
    _Float16* d = &lds[b][ldsoff];
    gload_lds16(s,        d);
    gload_lds16(s + 512,  d + 512);
    gload_lds16(s + 1024, d + 1024);
    gload_lds16(s + 1536, d + 1536);
  };
  auto body = [&](int b) {
    const _Float16* ldsK = &lds[b][0]    + lane * 8;
    const _Float16* ldsV = &lds[b][4096] + lane * 8;
    f32x4 sA[4], sB[4];
    __builtin_amdgcn_s_setprio(1);
#pragma unroll
    for (int c = 0; c < 4; ++c) {
      half8 k0 = *(const half8*)(ldsK + c*1024);
      half8 k1 = *(const half8*)(ldsK + c*1024 + 512);
      f32x4 tA = {}; tA = mfma16(k0, qa0, tA); tA = mfma16(k1, qa1, tA); sA[c] = tA;
      f32x4 tB = {}; tB = mfma16(k0, qb0, tB); tB = mfma16(k1, qb1, tB); sB[c] = tB;
    }
    __builtin_amdgcn_s_setprio(0);
    H8U a0, a1, b0, b1;
#pragma unroll
    for (int c = 0; c < 4; ++c) {
      float eA0 = __builtin_amdgcn_exp2f(sA[c][0]);
      float eA1 = __builtin_amdgcn_exp2f(sA[c][1]);
      float eA2 = __builtin_amdgcn_exp2f(sA[c][2]);
      float eA3 = __builtin_amdgcn_exp2f(sA[c][3]);
      float eB0 = __builtin_amdgcn_exp2f(sB[c][0]);
      float eB1 = __builtin_amdgcn_exp2f(sB[c][1]);
      float eB2 = __builtin_amdgcn_exp2f(sB[c][2]);
      float eB3 = __builtin_amdgcn_exp2f(sB[c][3]);
      H8U* da = (c < 2) ? &a0 : &a1;
      H8U* db = (c < 2) ? &b0 : &b1;
      int base = (c & 1) * 2;
      da->h2[base]     = __builtin_amdgcn_cvt_pkrtz(eA0, eA1);
      da->h2[base + 1] = __builtin_amdgcn_cvt_pkrtz(eA2, eA3);
      db->h2[base]     = __builtin_amdgcn_cvt_pkrtz(eB0, eB1);
      db->h2[base + 1] = __builtin_amdgcn_cvt_pkrtz(eB2, eB3);
    }
    __builtin_amdgcn_s_setprio(1);
#pragma unroll
    for (int cc = 0; cc < 4; ++cc) {
      half8 v0 = *(const half8*)(ldsV + cc*1024);
      half8 v1 = *(const half8*)(ldsV + cc*1024 + 512);
      accA[cc] = mfma16(v0, a0.h8, accA[cc]); accA[cc] = mfma16(v1, a1.h8, accA[cc]);
      accB[cc] = mfma16(v0, b0.h8, accB[cc]); accB[cc] = mfma16(v1, b1.h8, accB[cc]);
    }
    acclA = mfma16(ones, a0.h8, acclA); acclA = mfma16(ones, a1.h8, acclA);
    acclB = mfma16(ones, b0.h8, acclB); acclB = mfma16(ones, b1.h8, acclB);
    __builtin_amdgcn_s_setprio(0);
  };

  stage(0, 0);
#pragma unroll 1
  for (int t = 0; t < 9; ++t) {
    if (t < 8) {
      stage(t + 1, (t + 1) & 1);                       // 4 loads in flight
      asm volatile("s_waitcnt vmcnt(4)" ::: "memory"); // own stage(t) landed
    } else {
      asm volatile("s_waitcnt vmcnt(0)" ::: "memory");
    }
    __builtin_amdgcn_sched_barrier(0);
    __builtin_amdgcn_s_barrier();        // all waves' stage(t) landed
    __builtin_amdgcn_sched_barrier(0);
    body(t & 1);
    if (t < 8) {
      __builtin_amdgcn_sched_barrier(0);
      __builtin_amdgcn_s_barrier();      // all readers of buf done before overwrite
    }
  }

  float invA = 1.0f / acclA[0];
  float invB = 1.0f / acclB[0];
  _Float16* Oa = Opart + (((size_t)chunk * 16 + pair) * N_TOK + n0 + lr) * 64;
  _Float16* Ob = Oa + 16 * 64;
#pragma unroll
  for (int cc = 0; cc < 4; ++cc) {
    half4 ha, hb;
#pragma unroll
    for (int r = 0; r < 4; ++r) {
      ha[r] = (_Float16)(accA[cc][r] * invA);
      hb[r] = (_Float16)(accB[cc][r] * invB);
    }
    *(half4*)(Oa + 16*cc + 4*g4) = ha;
    *(half4*)(Ob + 16*cc + 4*g4) = hb;
  }
  if (g4 == 0) {
    Lpart[((size_t)chunk * 16 + pair) * N_TOK + n0 + lr] = acclA[0];
    Lpart[((size_t)chunk * 16 + pair) * N_TOK + n0 + 16 + lr] = acclB[0];
  }
}

// ---- kernel 4: merge split-K chunks (l-weighted), weight by c_g, sum over gk ----
__global__ __launch_bounds__(256) void k_combine(
    const _Float16* __restrict__ Opart, const float* __restrict__ Lpart,
    float* __restrict__ out) {
  int gid = blockIdx.x * 256 + threadIdx.x;   // 73728 total
  int hd = gid / (N_TOK * 8);
  int rem = gid % (N_TOK * 8);
  int n = rem >> 3, db = (rem & 7) * 8;
  float acc[8] = {};
#pragma unroll
  for (int gk = 0; gk < 4; ++gk) {
    float cg = (((hd - gk) & 3) == 2) ? 2.0f : 1.0f;
    int pair = hd * 4 + gk;
    float la[4], lsum = 0.f;
#pragma unroll
    for (int ch = 0; ch < 4; ++ch) {
      la[ch] = Lpart[((size_t)ch * 16 + pair) * N_TOK + n];
      lsum += la[ch];
    }
    float rs = cg / lsum;
#pragma unroll
    for (int ch = 0; ch < 4; ++ch) {
      half8 v = *(const half8*)(Opart + (((size_t)ch * 16 + pair) * N_TOK + n) * 64 + db);
      float w = la[ch] * rs;
#pragma unroll
      for (int i = 0; i < 8; ++i) acc[i] += w * (float)v[i];
    }
  }
  float* dst = out + (size_t)n * OUTC + hd * 64 + db;
  float4 r0, r1;
  r0.x = acc[0]; r0.y = acc[1]; r0.z = acc[2]; r0.w = acc[3];
  r1.x = acc[4]; r1.y = acc[5]; r1.z = acc[6]; r1.w = acc[7];
  *(float4*)(dst)     = r0;
  *(float4*)(dst + 4) = r1;
}

extern "C" void kernel_launch(void* const* d_in, const int* in_sizes, int n_in,
                              void* d_out, int out_size, void* d_ws, size_t ws_size,
                              hipStream_t stream) {
  (void)in_sizes; (void)n_in; (void)out_size; (void)ws_size;
  const float* x  = (const float*)d_in[0];
  const float* Wq = (const float*)d_in[1];
  const float* bq = (const float*)d_in[2];
  const float* Wk = (const float*)d_in[3];
  const float* bk = (const float*)d_in[4];
  const float* Wv = (const float*)d_in[5];
  const float* bv = (const float*)d_in[6];

  char* ws = (char*)d_ws;
  float*    Lp  = (float*)   (ws);              //   589,824 B
  _Float16* Qh  = (_Float16*)(ws + 1179648);    // 1,179,648 B
  _Float16* KF  = (_Float16*)(ws + 2359296);    // 1,179,648 B (fragment-major)
  float*    VfT = (float*)   (ws + 3538944);    // 2,359,296 B
  _Float16* VF  = (_Float16*)(ws + 5898240);    // 1,179,648 B (fragment-major)
  _Float16* Op  = (_Float16*)(ws + 7077888);    // 9,437,184 B (ends 16,515,072)
  float* out = (float*)d_out;

  k_proj   <<<dim3(36, 4, 3), dim3(256), 0, stream>>>(x, Wq, Wk, Wv, bq, bk, bv, Qh, KF, VfT);
  k_smooth <<<dim3(36, 4), dim3(256), 0, stream>>>(VfT, VF);
  k_flash  <<<dim3(18, 16, 4), dim3(256), 0, stream>>>(Qh, KF, VF, Op, Lp);
  k_combine<<<dim3(288), dim3(256), 0, stream>>>(Op, Lp, out);
}